// Round 1
// baseline (224.879 us; speedup 1.0000x reference)
//
#include <hip/hip_runtime.h>
#include <stdint.h>

#define N_ROWS 4096
#define N_DIM  2048
#define MARGIN 0.3f

typedef __attribute__((ext_vector_type(8))) short short8;
typedef __attribute__((ext_vector_type(4))) float floatx4;

__device__ inline unsigned short f2bf_rne(float f) {
  unsigned u = __float_as_uint(f);
  unsigned r = 0x7fffu + ((u >> 16) & 1u);
  return (unsigned short)((u + r) >> 16);
}
__device__ inline float bf2f(unsigned short h) {
  return __uint_as_float(((unsigned)h) << 16);
}

__device__ inline void global_load_lds16(const unsigned short* g, unsigned short* l) {
  __builtin_amdgcn_global_load_lds(
      (const __attribute__((address_space(1))) unsigned int*)g,
      (__attribute__((address_space(3))) unsigned int*)l,
      16 /*bytes per lane*/, 0, 0);
}

// ---------------------------------------------------------------------------
// Kernel 1: cast X -> bf16 (row-major, into ws), compute sq[i] = ||xbf_i||^2
// in fp32 from the ROUNDED values (so the diagonal of d2 is exactly 0), and
// init per-row reduction cells (ap=0 bits, an=FLT_MAX bits; ws is poisoned
// 0xAA every call so we must write these every launch).
// ---------------------------------------------------------------------------
__global__ __launch_bounds__(256) void prep_kernel(
    const float* __restrict__ X, unsigned short* __restrict__ Xbf,
    float* __restrict__ sq, unsigned* __restrict__ ap, unsigned* __restrict__ an)
{
  const int row = blockIdx.x;
  const int t = threadIdx.x;
  const float4* xr = (const float4*)(X + (size_t)row * N_DIM);
  ushort4* xb = (ushort4*)(Xbf + (size_t)row * N_DIM);
  float acc = 0.f;
#pragma unroll
  for (int j = 0; j < 2; ++j) {
    int idx = t + j * 256;                 // 512 float4 per row
    float4 v = xr[idx];
    ushort4 o;
    o.x = f2bf_rne(v.x); o.y = f2bf_rne(v.y);
    o.z = f2bf_rne(v.z); o.w = f2bf_rne(v.w);
    float a = bf2f(o.x), b = bf2f(o.y), c = bf2f(o.z), d = bf2f(o.w);
    acc += a * a + b * b + c * c + d * d;
    xb[idx] = o;
  }
#pragma unroll
  for (int m = 32; m >= 1; m >>= 1) acc += __shfl_down(acc, m, 64);
  __shared__ float wsum[4];
  const int lane = t & 63, w = t >> 6;
  if (lane == 0) wsum[w] = acc;
  __syncthreads();
  if (t == 0) {
    sq[row] = wsum[0] + wsum[1] + wsum[2] + wsum[3];
    ap[row] = 0u;           // max identity over nonneg floats
    an[row] = 0x7f7fffffu;  // FLT_MAX bits
  }
}

// ---------------------------------------------------------------------------
// Kernel 2: 128x128 tile of G = X X^T via bf16 MFMA, fused distance + mask +
// per-row hardest-positive(max)/hardest-negative(min), atomically merged into
// global per-row cells (ordered-uint trick; all distances >= 0).
//
// LDS layout trick: global_load_lds writes lane i at base+16*i. We define the
// tile layout so that slot i == (row=i&15, kchunk=i>>4) of a 16-row block;
// then the MFMA A/B fragment for lane l is exactly the contiguous 16 B at
// base + 16*l -> ds_read_b128, conflict-free, zero repacking.
// ---------------------------------------------------------------------------
__global__ __launch_bounds__(256) void dist_kernel(
    const unsigned short* __restrict__ Xbf, const float* __restrict__ sq,
    const int* __restrict__ lab, unsigned* __restrict__ ap, unsigned* __restrict__ an)
{
  __shared__ __align__(16) unsigned short As[128 * 32];  // 8 KB, 8 blocks of 16rows x 32k
  __shared__ __align__(16) unsigned short Bs[128 * 32];
  __shared__ float sqi[128], sqj[128];
  __shared__ int labi[128], labj[128];

  const int bi = blockIdx.x, bj = blockIdx.y;
  const int t = threadIdx.x;
  const int lane = t & 63, w = t >> 6;     // 4 waves
  const int wm = w >> 1, wn = w & 1;       // 2x2 wave grid, 64x64 per wave
  const int rowl = lane & 15, kbl = lane >> 4;

  if (t < 128) { int r = bi * 128 + t; sqi[t] = sq[r]; labi[t] = lab[r]; }
  else         { int c = bj * 128 + (t - 128); sqj[t - 128] = sq[c]; labj[t - 128] = lab[c]; }

  // Wave w stages rows [w*32, w*32+32) of both tiles as two 16-row blocks.
  const unsigned short* gA = Xbf + (size_t)(bi * 128 + w * 32 + rowl) * N_DIM + kbl * 8;
  const unsigned short* gB = Xbf + (size_t)(bj * 128 + w * 32 + rowl) * N_DIM + kbl * 8;
  unsigned short* lA = &As[w * 1024];
  unsigned short* lB = &Bs[w * 1024];

  floatx4 acc[4][4] = {};

  for (int k0 = 0; k0 < N_DIM; k0 += 32) {
    if (k0) __syncthreads();               // prev iteration's frag reads done
    global_load_lds16(gA + k0,              lA);
    global_load_lds16(gA + k0 + 16 * N_DIM, lA + 512);
    global_load_lds16(gB + k0,              lB);
    global_load_lds16(gB + k0 + 16 * N_DIM, lB + 512);
    __syncthreads();                       // drains vmcnt -> DMA data visible

    short8 af[4], bf[4];
#pragma unroll
    for (int mi = 0; mi < 4; ++mi)
      af[mi] = *(const short8*)&As[(wm * 4 + mi) * 512 + lane * 8];
#pragma unroll
    for (int ni = 0; ni < 4; ++ni)
      bf[ni] = *(const short8*)&Bs[(wn * 4 + ni) * 512 + lane * 8];
#pragma unroll
    for (int mi = 0; mi < 4; ++mi)
#pragma unroll
      for (int ni = 0; ni < 4; ++ni)
        acc[mi][ni] = __builtin_amdgcn_mfma_f32_16x16x32_bf16(af[mi], bf[ni], acc[mi][ni], 0, 0, 0);
  }

  // Epilogue. C/D layout (m89-verified): col = lane&15, row = (lane>>4)*4 + reg.
  const int cn = lane & 15, lg = lane >> 4;
  float sqc[4]; int labc[4];
#pragma unroll
  for (int ni = 0; ni < 4; ++ni) {
    int c = wn * 64 + ni * 16 + cn;
    sqc[ni] = sqj[c]; labc[ni] = labj[c];
  }
#pragma unroll
  for (int mi = 0; mi < 4; ++mi) {
#pragma unroll
    for (int r = 0; r < 4; ++r) {
      const int rl = wm * 64 + mi * 16 + lg * 4 + r;   // row within 128-tile
      const float si = sqi[rl];
      const int li = labi[rl];
      float apv = 0.0f;                   // identity: dist >= 1e-6 > 0 always
      float anv = 3.402823466e+38f;
#pragma unroll
      for (int ni = 0; ni < 4; ++ni) {
        float g = acc[mi][ni][r];
        float d2 = fmaf(-2.0f, g, si + sqc[ni]);
        d2 = fmaxf(d2, 1e-12f);
        float d = __builtin_amdgcn_sqrtf(d2);
        bool same = (li == labc[ni]);
        apv = fmaxf(apv, same ? d : 0.0f);
        anv = fminf(anv, same ? 3.402823466e+38f : d);
      }
      // reduce over the 16 lanes holding this row's 64 columns
#pragma unroll
      for (int m = 8; m >= 1; m >>= 1) {
        apv = fmaxf(apv, __shfl_xor(apv, m, 64));
        anv = fminf(anv, __shfl_xor(anv, m, 64));
      }
      if (cn == 0) {
        int R = bi * 128 + rl;
        atomicMax(&ap[R], __float_as_uint(apv));
        atomicMin(&an[R], __float_as_uint(anv));
      }
    }
  }
}

// ---------------------------------------------------------------------------
// Kernel 3: loss = mean(relu(margin + dist_ap - dist_an))
// ---------------------------------------------------------------------------
__global__ __launch_bounds__(256) void finalize_kernel(
    const unsigned* __restrict__ ap, const unsigned* __restrict__ an,
    float* __restrict__ out)
{
  const int t = threadIdx.x;
  float s = 0.f;
  for (int i = t; i < N_ROWS; i += 256) {
    float a = __uint_as_float(ap[i]);
    float b = __uint_as_float(an[i]);
    s += fmaxf(MARGIN + a - b, 0.0f);
  }
#pragma unroll
  for (int m = 32; m >= 1; m >>= 1) s += __shfl_down(s, m, 64);
  __shared__ float wsum[4];
  const int lane = t & 63, w = t >> 6;
  if (lane == 0) wsum[w] = s;
  __syncthreads();
  if (t == 0) out[0] = (wsum[0] + wsum[1] + wsum[2] + wsum[3]) * (1.0f / N_ROWS);
}

extern "C" void kernel_launch(void* const* d_in, const int* in_sizes, int n_in,
                              void* d_out, int out_size, void* d_ws, size_t ws_size,
                              hipStream_t stream) {
  const float* X = (const float*)d_in[0];
  const int* lab = (const int*)d_in[1];
  float* out = (float*)d_out;

  char* ws = (char*)d_ws;
  unsigned short* Xbf = (unsigned short*)ws;                          // 16 MB
  float* sq  = (float*)(ws + (size_t)N_ROWS * N_DIM * 2);             // 16 KB
  unsigned* ap = (unsigned*)((char*)sq + N_ROWS * sizeof(float));     // 16 KB
  unsigned* an = (unsigned*)((char*)ap + N_ROWS * sizeof(unsigned));  // 16 KB

  prep_kernel<<<N_ROWS, 256, 0, stream>>>(X, Xbf, sq, ap, an);
  dist_kernel<<<dim3(32, 32), 256, 0, stream>>>(Xbf, sq, lab, ap, an);
  finalize_kernel<<<1, 256, 0, stream>>>(ap, an, out);
}

// Round 2
// 212.599 us; speedup vs baseline: 1.0578x; 1.0578x over previous
//
#include <hip/hip_runtime.h>
#include <stdint.h>

#define N_ROWS 4096
#define N_DIM  2048
#define MARGIN 0.3f
#define NTILE  32            // 4096 / 128 tiles per side
#define FLTMAX 3.402823466e+38f

typedef __attribute__((ext_vector_type(8))) short short8;
typedef __attribute__((ext_vector_type(4))) float floatx4;

__device__ inline unsigned short f2bf_rne(float f) {
  unsigned u = __float_as_uint(f);
  unsigned r = 0x7fffu + ((u >> 16) & 1u);
  return (unsigned short)((u + r) >> 16);
}
__device__ inline float bf2f(unsigned short h) {
  return __uint_as_float(((unsigned)h) << 16);
}

__device__ inline void global_load_lds16(const unsigned short* g, unsigned short* l) {
  __builtin_amdgcn_global_load_lds(
      (const __attribute__((address_space(1))) unsigned int*)g,
      (__attribute__((address_space(3))) unsigned int*)l,
      16 /*bytes per lane*/, 0, 0);
}

// ---------------------------------------------------------------------------
// Kernel 1: cast X -> bf16 (into ws), sq[i] = ||xbf_i||^2 in fp32 from the
// ROUNDED values (diagonal of d2 ~ 0), init per-row reduction cells.
// ---------------------------------------------------------------------------
__global__ __launch_bounds__(256) void prep_kernel(
    const float* __restrict__ X, unsigned short* __restrict__ Xbf,
    float* __restrict__ sq, unsigned* __restrict__ ap, unsigned* __restrict__ an)
{
  const int row = blockIdx.x;
  const int t = threadIdx.x;
  const float4* xr = (const float4*)(X + (size_t)row * N_DIM);
  ushort4* xb = (ushort4*)(Xbf + (size_t)row * N_DIM);
  float acc = 0.f;
#pragma unroll
  for (int j = 0; j < 2; ++j) {
    int idx = t + j * 256;                 // 512 float4 per row
    float4 v = xr[idx];
    ushort4 o;
    o.x = f2bf_rne(v.x); o.y = f2bf_rne(v.y);
    o.z = f2bf_rne(v.z); o.w = f2bf_rne(v.w);
    float a = bf2f(o.x), b = bf2f(o.y), c = bf2f(o.z), d = bf2f(o.w);
    acc += a * a + b * b + c * c + d * d;
    xb[idx] = o;
  }
#pragma unroll
  for (int m = 32; m >= 1; m >>= 1) acc += __shfl_down(acc, m, 64);
  __shared__ float wsum[4];
  const int lane = t & 63, w = t >> 6;
  if (lane == 0) wsum[w] = acc;
  __syncthreads();
  if (t == 0) {
    sq[row] = wsum[0] + wsum[1] + wsum[2] + wsum[3];
    ap[row] = 0u;           // max identity (dist >= 0)
    an[row] = 0x7f7fffffu;  // FLT_MAX bits
  }
}

// ---------------------------------------------------------------------------
// Kernel 2: upper-triangle 128x128 tiles of G = X X^T via bf16 MFMA with
// double-buffered LDS prefetch (1 barrier / K-iter). Each wave's 64x64
// sub-tile feeds BOTH the row-side reduction (over cn lanes) and, by
// symmetry d(i,j)=d(j,i), the col-side reduction (over lg lanes). Max/min
// are idempotent so the diagonal tile's double count is harmless.
// ---------------------------------------------------------------------------
__global__ __launch_bounds__(256) void dist_kernel(
    const unsigned short* __restrict__ Xbf, const float* __restrict__ sq,
    const int* __restrict__ lab, unsigned* __restrict__ ap, unsigned* __restrict__ an)
{
  __shared__ __align__(16) unsigned short As[2][128 * 32];  // 2 x 8 KB
  __shared__ __align__(16) unsigned short Bs[2][128 * 32];
  __shared__ float sqi[128], sqj[128];
  __shared__ int labi[128], labj[128];

  // decode linear block id -> (bi, bj) with bi <= bj (uniform scalar loop)
  int rem = blockIdx.x;
  int bi = 0;
  while (rem >= NTILE - bi) { rem -= NTILE - bi; ++bi; }
  const int bj = bi + rem;

  const int t = threadIdx.x;
  const int lane = t & 63, w = t >> 6;     // 4 waves
  const int wm = w >> 1, wn = w & 1;       // 2x2 wave grid, 64x64 per wave
  const int rowl = lane & 15, kbl = lane >> 4;

  if (t < 128) { int r = bi * 128 + t; sqi[t] = sq[r]; labi[t] = lab[r]; }
  else         { int c = bj * 128 + (t - 128); sqj[t - 128] = sq[c]; labj[t - 128] = lab[c]; }

  const unsigned short* gA = Xbf + (size_t)(bi * 128 + w * 32 + rowl) * N_DIM + kbl * 8;
  const unsigned short* gB = Xbf + (size_t)(bj * 128 + w * 32 + rowl) * N_DIM + kbl * 8;

  floatx4 acc[4][4] = {};

  // prologue: stage tile 0 into buffer 0
  global_load_lds16(gA,              &As[0][w * 1024]);
  global_load_lds16(gA + 16 * N_DIM, &As[0][w * 1024 + 512]);
  global_load_lds16(gB,              &Bs[0][w * 1024]);
  global_load_lds16(gB + 16 * N_DIM, &Bs[0][w * 1024 + 512]);
  __syncthreads();   // compiler drains vmcnt(0) here -> tile 0 visible

  for (int it = 0; it < N_DIM / 32; ++it) {
    const int cur = it & 1, nxt = cur ^ 1;
    if (it + 1 < N_DIM / 32) {
      const int k = (it + 1) * 32;
      // prefetch next tile; DMA flight overlaps this iteration's compute
      global_load_lds16(gA + k,              &As[nxt][w * 1024]);
      global_load_lds16(gA + k + 16 * N_DIM, &As[nxt][w * 1024 + 512]);
      global_load_lds16(gB + k,              &Bs[nxt][w * 1024]);
      global_load_lds16(gB + k + 16 * N_DIM, &Bs[nxt][w * 1024 + 512]);
    }
    short8 af[4], bf[4];
#pragma unroll
    for (int mi = 0; mi < 4; ++mi)
      af[mi] = *(const short8*)&As[cur][(wm * 4 + mi) * 512 + lane * 8];
#pragma unroll
    for (int ni = 0; ni < 4; ++ni)
      bf[ni] = *(const short8*)&Bs[cur][(wn * 4 + ni) * 512 + lane * 8];
#pragma unroll
    for (int mi = 0; mi < 4; ++mi)
#pragma unroll
      for (int ni = 0; ni < 4; ++ni)
        acc[mi][ni] = __builtin_amdgcn_mfma_f32_16x16x32_bf16(af[mi], bf[ni], acc[mi][ni], 0, 0, 0);
    __syncthreads();   // drains prefetch DMA + fences cur-buffer reuse
  }

  // Epilogue. C/D layout (m89): col = lane&15, row = (lane>>4)*4 + reg.
  const int cn = lane & 15, lg = lane >> 4;
  float sqc[4]; int labc[4];
#pragma unroll
  for (int ni = 0; ni < 4; ++ni) {
    int c = wn * 64 + ni * 16 + cn;
    sqc[ni] = sqj[c]; labc[ni] = labj[c];
  }
  float cap[4] = {0.f, 0.f, 0.f, 0.f};
  float can[4] = {FLTMAX, FLTMAX, FLTMAX, FLTMAX};
#pragma unroll
  for (int mi = 0; mi < 4; ++mi) {
#pragma unroll
    for (int r = 0; r < 4; ++r) {
      const int rl = wm * 64 + mi * 16 + lg * 4 + r;   // row within 128-tile
      const float si = sqi[rl];
      const int li = labi[rl];
      float apv = 0.0f;
      float anv = FLTMAX;
#pragma unroll
      for (int ni = 0; ni < 4; ++ni) {
        float g = acc[mi][ni][r];
        float d2 = fmaf(-2.0f, g, si + sqc[ni]);
        d2 = fmaxf(d2, 1e-12f);
        float d = __builtin_amdgcn_sqrtf(d2);
        const bool same = (li == labc[ni]);
        const float dp = same ? d : 0.0f;
        const float dn = same ? FLTMAX : d;
        apv = fmaxf(apv, dp);
        anv = fminf(anv, dn);
        cap[ni] = fmaxf(cap[ni], dp);   // col-side (symmetric) partials
        can[ni] = fminf(can[ni], dn);
      }
      // row side: reduce the 16 lanes (cn) holding this row's 64 columns
#pragma unroll
      for (int m = 8; m >= 1; m >>= 1) {
        apv = fmaxf(apv, __shfl_xor(apv, m, 64));
        anv = fminf(anv, __shfl_xor(anv, m, 64));
      }
      if (cn == 0) {
        int R = bi * 128 + rl;
        atomicMax(&ap[R], __float_as_uint(apv));
        atomicMin(&an[R], __float_as_uint(anv));
      }
    }
  }
  // col side: reduce over the 4 lane-groups (lg) holding this column's rows
#pragma unroll
  for (int ni = 0; ni < 4; ++ni) {
    float a = cap[ni], b = can[ni];
#pragma unroll
    for (int m = 16; m <= 32; m <<= 1) {
      a = fmaxf(a, __shfl_xor(a, m, 64));
      b = fminf(b, __shfl_xor(b, m, 64));
    }
    if (lg == 0) {
      int C = bj * 128 + wn * 64 + ni * 16 + cn;
      atomicMax(&ap[C], __float_as_uint(a));
      atomicMin(&an[C], __float_as_uint(b));
    }
  }
}

// ---------------------------------------------------------------------------
// Kernel 3: loss = mean(relu(margin + dist_ap - dist_an))
// ---------------------------------------------------------------------------
__global__ __launch_bounds__(256) void finalize_kernel(
    const unsigned* __restrict__ ap, const unsigned* __restrict__ an,
    float* __restrict__ out)
{
  const int t = threadIdx.x;
  float s = 0.f;
  for (int i = t; i < N_ROWS; i += 256) {
    float a = __uint_as_float(ap[i]);
    float b = __uint_as_float(an[i]);
    s += fmaxf(MARGIN + a - b, 0.0f);
  }
#pragma unroll
  for (int m = 32; m >= 1; m >>= 1) s += __shfl_down(s, m, 64);
  __shared__ float wsum[4];
  const int lane = t & 63, w = t >> 6;
  if (lane == 0) wsum[w] = s;
  __syncthreads();
  if (t == 0) out[0] = (wsum[0] + wsum[1] + wsum[2] + wsum[3]) * (1.0f / N_ROWS);
}

extern "C" void kernel_launch(void* const* d_in, const int* in_sizes, int n_in,
                              void* d_out, int out_size, void* d_ws, size_t ws_size,
                              hipStream_t stream) {
  const float* X = (const float*)d_in[0];
  const int* lab = (const int*)d_in[1];
  float* out = (float*)d_out;

  char* ws = (char*)d_ws;
  unsigned short* Xbf = (unsigned short*)ws;                          // 16 MB
  float* sq  = (float*)(ws + (size_t)N_ROWS * N_DIM * 2);             // 16 KB
  unsigned* ap = (unsigned*)((char*)sq + N_ROWS * sizeof(float));     // 16 KB
  unsigned* an = (unsigned*)((char*)ap + N_ROWS * sizeof(unsigned));  // 16 KB

  prep_kernel<<<N_ROWS, 256, 0, stream>>>(X, Xbf, sq, ap, an);
  dist_kernel<<<NTILE * (NTILE + 1) / 2, 256, 0, stream>>>(Xbf, sq, lab, ap, an);
  finalize_kernel<<<1, 256, 0, stream>>>(ap, an, out);
}

// Round 3
// 203.218 us; speedup vs baseline: 1.1066x; 1.0462x over previous
//
#include <hip/hip_runtime.h>
#include <stdint.h>

#define N_ROWS 4096
#define N_DIM  2048
#define MARGIN 0.3f
#define NTILE  32            // 4096 / 128 col-tiles
#define FLTMAX 3.402823466e+38f

typedef __attribute__((ext_vector_type(8))) short short8;
typedef __attribute__((ext_vector_type(4))) float floatx4;

__device__ inline unsigned short f2bf_rne(float f) {
  unsigned u = __float_as_uint(f);
  unsigned r = 0x7fffu + ((u >> 16) & 1u);
  return (unsigned short)((u + r) >> 16);
}
__device__ inline float bf2f(unsigned short h) {
  return __uint_as_float(((unsigned)h) << 16);
}

__device__ inline void global_load_lds16(const unsigned short* g, unsigned short* l) {
  __builtin_amdgcn_global_load_lds(
      (const __attribute__((address_space(1))) unsigned int*)g,
      (__attribute__((address_space(3))) unsigned int*)l,
      16 /*bytes per lane*/, 0, 0);
}

// ---------------------------------------------------------------------------
// Kernel 1: cast X -> bf16, sq from ROUNDED values, init reduction cells.
// One WAVE per row: no __syncthreads, no LDS, pure wave-shuffle reduce.
// ---------------------------------------------------------------------------
__global__ __launch_bounds__(256) void prep_kernel(
    const float* __restrict__ X, unsigned short* __restrict__ Xbf,
    float* __restrict__ sq, unsigned* __restrict__ ap, unsigned* __restrict__ an)
{
  const int t = threadIdx.x;
  const int lane = t & 63, w = t >> 6;
  const int row = blockIdx.x * 4 + w;
  const float4* xr = (const float4*)(X + (size_t)row * N_DIM);
  ushort4* xb = (ushort4*)(Xbf + (size_t)row * N_DIM);
  float acc = 0.f;
#pragma unroll
  for (int j = 0; j < 8; ++j) {          // 512 float4 per row / 64 lanes
    int idx = lane + j * 64;
    float4 v = xr[idx];
    ushort4 o;
    o.x = f2bf_rne(v.x); o.y = f2bf_rne(v.y);
    o.z = f2bf_rne(v.z); o.w = f2bf_rne(v.w);
    float a = bf2f(o.x), b = bf2f(o.y), c = bf2f(o.z), d = bf2f(o.w);
    acc += a * a + b * b + c * c + d * d;
    xb[idx] = o;
  }
#pragma unroll
  for (int m = 32; m >= 1; m >>= 1) acc += __shfl_down(acc, m, 64);
  if (lane == 0) {
    sq[row] = acc;
    ap[row] = 0u;           // max identity (dist >= 0)
    an[row] = 0x7f7fffffu;  // FLT_MAX bits
  }
}

// ---------------------------------------------------------------------------
// Kernel 2: upper-triangle tile-pairs (bi<=bj) at 128x128, each SPLIT into
// two 64x128 blocks (h=0,1) -> grid 1056 ~ 4.1 blocks/CU (VGPR-128 residency
// cap). BK=64, single LDS buffer (26 KB), m97 2-barrier K-loop: 32 fat
// iterations instead of 64 thin ones. Each wave (1x4 grid, 64 rows x 32 cols)
// feeds BOTH the row-side and, by d(i,j)=d(j,i), the col-side reduction.
// ---------------------------------------------------------------------------
__global__ __launch_bounds__(256, 4) void dist_kernel(
    const unsigned short* __restrict__ Xbf, const float* __restrict__ sq,
    const int* __restrict__ lab, unsigned* __restrict__ ap, unsigned* __restrict__ an)
{
  __shared__ __align__(16) unsigned short As[8 * 512];   //  8 KB: 4 rg x 2 kh slots
  __shared__ __align__(16) unsigned short Bs[16 * 512];  // 16 KB: 8 rg x 2 kh slots
  __shared__ float sqi[64], sqj[128];
  __shared__ int labi[64], labj[128];

  // decode: pair p (bi<=bj) + half h
  int p = blockIdx.x >> 1;
  const int h = blockIdx.x & 1;
  int bi = 0;
  while (p >= NTILE - bi) { p -= NTILE - bi; ++bi; }
  const int bj = bi + p;

  const int t = threadIdx.x;
  const int lane = t & 63, w = t >> 6;     // 4 waves; wave w = col block [w*32, w*32+32)
  const int rowl = lane & 15, kbl = lane >> 4;

  if (t < 64)                { int r = bi * 128 + h * 64 + t; sqi[t] = sq[r]; labi[t] = lab[r]; }
  else if (t < 192)          { int c = bj * 128 + (t - 64);   sqj[t - 64] = sq[c]; labj[t - 64] = lab[c]; }

  // staging sources: wave w stages A row-group w and B row-groups 2w, 2w+1
  const unsigned short* gA  = Xbf + (size_t)(bi * 128 + h * 64 + w * 16 + rowl) * N_DIM + kbl * 8;
  const unsigned short* gB0 = Xbf + (size_t)(bj * 128 + (2 * w) * 16 + rowl) * N_DIM + kbl * 8;
  const unsigned short* gB1 = Xbf + (size_t)(bj * 128 + (2 * w + 1) * 16 + rowl) * N_DIM + kbl * 8;

  floatx4 acc[4][2] = {};

  for (int it = 0; it < N_DIM / 64; ++it) {
    const int k0 = it * 64;
    if (it) __syncthreads();               // LDS reuse fence
    global_load_lds16(gA + k0,       &As[(w * 2 + 0) * 512]);
    global_load_lds16(gA + k0 + 32,  &As[(w * 2 + 1) * 512]);
    global_load_lds16(gB0 + k0,      &Bs[((2 * w) * 2 + 0) * 512]);
    global_load_lds16(gB0 + k0 + 32, &Bs[((2 * w) * 2 + 1) * 512]);
    global_load_lds16(gB1 + k0,      &Bs[((2 * w + 1) * 2 + 0) * 512]);
    global_load_lds16(gB1 + k0 + 32, &Bs[((2 * w + 1) * 2 + 1) * 512]);
    __syncthreads();                       // drains vmcnt -> DMA data visible

#pragma unroll
    for (int kh = 0; kh < 2; ++kh) {
      short8 af[4], bfr[2];
#pragma unroll
      for (int mi = 0; mi < 4; ++mi)
        af[mi] = *(const short8*)&As[(mi * 2 + kh) * 512 + lane * 8];
#pragma unroll
      for (int ni = 0; ni < 2; ++ni)
        bfr[ni] = *(const short8*)&Bs[((w * 2 + ni) * 2 + kh) * 512 + lane * 8];
#pragma unroll
      for (int mi = 0; mi < 4; ++mi)
#pragma unroll
        for (int ni = 0; ni < 2; ++ni)
          acc[mi][ni] = __builtin_amdgcn_mfma_f32_16x16x32_bf16(af[mi], bfr[ni], acc[mi][ni], 0, 0, 0);
    }
  }

  // Epilogue. C/D layout (m89): col = lane&15, row = (lane>>4)*4 + reg.
  const int cn = lane & 15, lg = lane >> 4;
  float sqc[2]; int labc[2];
#pragma unroll
  for (int ni = 0; ni < 2; ++ni) {
    int c = w * 32 + ni * 16 + cn;
    sqc[ni] = sqj[c]; labc[ni] = labj[c];
  }
  float cap[2] = {0.f, 0.f};
  float can[2] = {FLTMAX, FLTMAX};
#pragma unroll
  for (int mi = 0; mi < 4; ++mi) {
#pragma unroll
    for (int r = 0; r < 4; ++r) {
      const int rl = mi * 16 + lg * 4 + r;   // row within this 64-row half
      const float si = sqi[rl];
      const int li = labi[rl];
      float apv = 0.0f;
      float anv = FLTMAX;
#pragma unroll
      for (int ni = 0; ni < 2; ++ni) {
        float g = acc[mi][ni][r];
        float d2 = fmaf(-2.0f, g, si + sqc[ni]);
        d2 = fmaxf(d2, 1e-12f);
        float d = __builtin_amdgcn_sqrtf(d2);
        const bool same = (li == labc[ni]);
        const float dp = same ? d : 0.0f;
        const float dn = same ? FLTMAX : d;
        apv = fmaxf(apv, dp);
        anv = fminf(anv, dn);
        cap[ni] = fmaxf(cap[ni], dp);   // col-side (symmetric) partials
        can[ni] = fminf(can[ni], dn);
      }
      // row side: reduce over the 16 cn-lanes (same lg = same row)
#pragma unroll
      for (int m = 8; m >= 1; m >>= 1) {
        apv = fmaxf(apv, __shfl_xor(apv, m, 64));
        anv = fminf(anv, __shfl_xor(anv, m, 64));
      }
      if (cn == 0) {
        int R = bi * 128 + h * 64 + rl;
        atomicMax(&ap[R], __float_as_uint(apv));
        atomicMin(&an[R], __float_as_uint(anv));
      }
    }
  }
  // col side: reduce over lg (xor 16,32) -> full 64 rows per column
#pragma unroll
  for (int ni = 0; ni < 2; ++ni) {
    float a = cap[ni], b = can[ni];
#pragma unroll
    for (int m = 16; m <= 32; m <<= 1) {
      a = fmaxf(a, __shfl_xor(a, m, 64));
      b = fminf(b, __shfl_xor(b, m, 64));
    }
    if (lg == 0) {
      int C = bj * 128 + w * 32 + ni * 16 + cn;
      atomicMax(&ap[C], __float_as_uint(a));
      atomicMin(&an[C], __float_as_uint(b));
    }
  }
}

// ---------------------------------------------------------------------------
// Kernel 3: loss = mean(relu(margin + dist_ap - dist_an))
// ---------------------------------------------------------------------------
__global__ __launch_bounds__(256) void finalize_kernel(
    const unsigned* __restrict__ ap, const unsigned* __restrict__ an,
    float* __restrict__ out)
{
  const int t = threadIdx.x;
  float s = 0.f;
  for (int i = t; i < N_ROWS; i += 256) {
    float a = __uint_as_float(ap[i]);
    float b = __uint_as_float(an[i]);
    s += fmaxf(MARGIN + a - b, 0.0f);
  }
#pragma unroll
  for (int m = 32; m >= 1; m >>= 1) s += __shfl_down(s, m, 64);
  __shared__ float wsum[4];
  const int lane = t & 63, w = t >> 6;
  if (lane == 0) wsum[w] = s;
  __syncthreads();
  if (t == 0) out[0] = (wsum[0] + wsum[1] + wsum[2] + wsum[3]) * (1.0f / N_ROWS);
}

extern "C" void kernel_launch(void* const* d_in, const int* in_sizes, int n_in,
                              void* d_out, int out_size, void* d_ws, size_t ws_size,
                              hipStream_t stream) {
  const float* X = (const float*)d_in[0];
  const int* lab = (const int*)d_in[1];
  float* out = (float*)d_out;

  char* ws = (char*)d_ws;
  unsigned short* Xbf = (unsigned short*)ws;                          // 16 MB
  float* sq  = (float*)(ws + (size_t)N_ROWS * N_DIM * 2);             // 16 KB
  unsigned* ap = (unsigned*)((char*)sq + N_ROWS * sizeof(float));     // 16 KB
  unsigned* an = (unsigned*)((char*)ap + N_ROWS * sizeof(unsigned));  // 16 KB

  prep_kernel<<<N_ROWS / 4, 256, 0, stream>>>(X, Xbf, sq, ap, an);
  dist_kernel<<<NTILE * (NTILE + 1), 256, 0, stream>>>(Xbf, sq, lab, ap, an);
  finalize_kernel<<<1, 256, 0, stream>>>(ap, an, out);
}

// Round 4
// 174.352 us; speedup vs baseline: 1.2898x; 1.1656x over previous
//
#include <hip/hip_runtime.h>
#include <stdint.h>

#define N_ROWS 4096
#define N_DIM  2048
#define MARGIN 0.3f
#define NTILE  32            // 4096 / 128 tiles per side
#define NITER  (N_DIM / 64)  // BK=64 -> 32 K-iterations
#define FLTMAX 3.402823466e+38f

typedef __attribute__((ext_vector_type(8))) short short8;
typedef __attribute__((ext_vector_type(4))) float floatx4;

__device__ inline unsigned short f2bf_rne(float f) {
  unsigned u = __float_as_uint(f);
  unsigned r = 0x7fffu + ((u >> 16) & 1u);
  return (unsigned short)((u + r) >> 16);
}
__device__ inline float bf2f(unsigned short h) {
  return __uint_as_float(((unsigned)h) << 16);
}

// ---------------------------------------------------------------------------
// Kernel 1: cast X -> bf16, sq from ROUNDED values, init reduction cells.
// One wave per row: no barriers, no LDS.
// ---------------------------------------------------------------------------
__global__ __launch_bounds__(256) void prep_kernel(
    const float* __restrict__ X, unsigned short* __restrict__ Xbf,
    float* __restrict__ sq, unsigned* __restrict__ ap, unsigned* __restrict__ an)
{
  const int t = threadIdx.x;
  const int lane = t & 63, w = t >> 6;
  const int row = blockIdx.x * 4 + w;
  const float4* xr = (const float4*)(X + (size_t)row * N_DIM);
  ushort4* xb = (ushort4*)(Xbf + (size_t)row * N_DIM);
  float acc = 0.f;
#pragma unroll
  for (int j = 0; j < 8; ++j) {          // 512 float4 per row / 64 lanes
    int idx = lane + j * 64;
    float4 v = xr[idx];
    ushort4 o;
    o.x = f2bf_rne(v.x); o.y = f2bf_rne(v.y);
    o.z = f2bf_rne(v.z); o.w = f2bf_rne(v.w);
    float a = bf2f(o.x), b = bf2f(o.y), c = bf2f(o.z), d = bf2f(o.w);
    acc += a * a + b * b + c * c + d * d;
    xb[idx] = o;
  }
#pragma unroll
  for (int m = 32; m >= 1; m >>= 1) acc += __shfl_down(acc, m, 64);
  if (lane == 0) {
    sq[row] = acc;
    ap[row] = 0u;           // max identity (dist >= 0)
    an[row] = 0x7f7fffffu;  // FLT_MAX bits
  }
}

// ---------------------------------------------------------------------------
// Kernel 2: upper-triangle 128x128 tiles of G = X X^T. Staging is
// buffer_load -> VGPR -> ds_write (NOT global_load_lds: that path measures
// ~15 B/cyc/CU and serializes all co-resident blocks — R1-R3 evidence).
// Pipeline per iter: issue tile k+1 global loads -> compute tile k from LDS
// (covers load latency) -> barrier -> ds_write -> barrier.
// LDS layout: fragment-ordered slots s = rowgroup*2 + kh, lane l's 16 B at
// slot*1024 + l*16 (row = rg*16 + (l&15), k = kh*32 + (l>>4)*8). Identity
// chunk map: thread t writes LDS chunk p*256+t, so its global source is
// row = (2p + (w>>1))*16 + (lane&15), k8 = (w&1)*4 + (lane>>4).
// Each wave's 64x64 output feeds BOTH row-side and (symmetry) col-side
// hardest-pos/neg reductions.
// ---------------------------------------------------------------------------
__global__ __launch_bounds__(256, 2) void dist_kernel(
    const unsigned short* __restrict__ Xbf, const float* __restrict__ sq,
    const int* __restrict__ lab, unsigned* __restrict__ ap, unsigned* __restrict__ an)
{
  __shared__ __align__(16) unsigned short As[8192];   // 16 KB: 16 slots x 512
  __shared__ __align__(16) unsigned short Bs[8192];   // 16 KB
  __shared__ float sqi[128], sqj[128];
  __shared__ int labi[128], labj[128];

  // decode linear block id -> (bi, bj) with bi <= bj
  int p = blockIdx.x;
  int bi = 0;
  while (p >= NTILE - bi) { p -= NTILE - bi; ++bi; }
  const int bj = bi + p;
  const bool offdiag = (bi != bj);

  const int t = threadIdx.x;
  const int lane = t & 63, w = t >> 6;     // 4 waves
  const int wm = w >> 1, wn = w & 1;       // 2x2 wave grid, 64x64 per wave

  if (t < 128) { int r = bi * 128 + t; sqi[t] = sq[r]; labi[t] = lab[r]; }
  else         { int c = bj * 128 + (t - 128); sqj[t - 128] = sq[c]; labj[t - 128] = lab[c]; }

  // per-thread staging coordinates (identity chunk map, see header comment)
  const int k8 = (w & 1) * 4 + (lane >> 4);            // which 8-elem k chunk
  size_t offA[4], offB[4];
#pragma unroll
  for (int pp = 0; pp < 4; ++pp) {
    const int row = (2 * pp + (w >> 1)) * 16 + (lane & 15);
    offA[pp] = (size_t)(bi * 128 + row) * N_DIM + k8 * 8;
    offB[pp] = (size_t)(bj * 128 + row) * N_DIM + k8 * 8;
  }

  short8 ra[4], rb[4];
#define LOAD_TILE(K0)                                                        \
  do {                                                                       \
    _Pragma("unroll")                                                        \
    for (int pp = 0; pp < 4; ++pp) {                                         \
      ra[pp] = *(const short8*)(Xbf + offA[pp] + (K0));                      \
      if (offdiag) rb[pp] = *(const short8*)(Xbf + offB[pp] + (K0));         \
    }                                                                        \
  } while (0)
#define STORE_TILE()                                                         \
  do {                                                                       \
    _Pragma("unroll")                                                        \
    for (int pp = 0; pp < 4; ++pp) {                                         \
      *(short8*)&As[(pp * 256 + t) * 8] = ra[pp];                            \
      if (offdiag) *(short8*)&Bs[(pp * 256 + t) * 8] = rb[pp];               \
    }                                                                        \
  } while (0)

  const unsigned short* Bbase = offdiag ? Bs : As;     // diagonal: B tile == A tile

  LOAD_TILE(0);
  STORE_TILE();
  __syncthreads();

  floatx4 acc[4][4] = {};

  for (int it = 0; it < NITER; ++it) {
    const bool has_next = (it + 1 < NITER);
    if (has_next) LOAD_TILE((it + 1) * 64);   // async into VGPRs, overlaps compute

#pragma unroll
    for (int kh = 0; kh < 2; ++kh) {
      short8 af[4], bfv[4];
#pragma unroll
      for (int mi = 0; mi < 4; ++mi)
        af[mi] = *(const short8*)&As[((wm * 4 + mi) * 2 + kh) * 512 + lane * 8];
#pragma unroll
      for (int ni = 0; ni < 4; ++ni)
        bfv[ni] = *(const short8*)&Bbase[((wn * 4 + ni) * 2 + kh) * 512 + lane * 8];
#pragma unroll
      for (int mi = 0; mi < 4; ++mi)
#pragma unroll
        for (int ni = 0; ni < 4; ++ni)
          acc[mi][ni] = __builtin_amdgcn_mfma_f32_16x16x32_bf16(af[mi], bfv[ni], acc[mi][ni], 0, 0, 0);
    }

    if (has_next) {
      __syncthreads();     // all LDS reads of tile `it` done
      STORE_TILE();        // compiler inserts vmcnt wait; loads mostly landed
      __syncthreads();     // tile it+1 visible
    }
  }

  // Epilogue. C/D layout (m89): col = lane&15, row = (lane>>4)*4 + reg.
  const int cn = lane & 15, lg = lane >> 4;
  float sqc[4]; int labc[4];
#pragma unroll
  for (int ni = 0; ni < 4; ++ni) {
    int c = wn * 64 + ni * 16 + cn;
    sqc[ni] = sqj[c]; labc[ni] = labj[c];
  }
  float cap[4] = {0.f, 0.f, 0.f, 0.f};
  float can[4] = {FLTMAX, FLTMAX, FLTMAX, FLTMAX};
#pragma unroll
  for (int mi = 0; mi < 4; ++mi) {
#pragma unroll
    for (int r = 0; r < 4; ++r) {
      const int rl = wm * 64 + mi * 16 + lg * 4 + r;   // row within 128-tile
      const float si = sqi[rl];
      const int li = labi[rl];
      float apv = 0.0f;
      float anv = FLTMAX;
#pragma unroll
      for (int ni = 0; ni < 4; ++ni) {
        float g = acc[mi][ni][r];
        float d2 = fmaf(-2.0f, g, si + sqc[ni]);
        d2 = fmaxf(d2, 1e-12f);
        float d = __builtin_amdgcn_sqrtf(d2);
        const bool same = (li == labc[ni]);
        const float dp = same ? d : 0.0f;
        const float dn = same ? FLTMAX : d;
        apv = fmaxf(apv, dp);
        anv = fminf(anv, dn);
        cap[ni] = fmaxf(cap[ni], dp);   // col-side (symmetric) partials
        can[ni] = fminf(can[ni], dn);
      }
      // row side: reduce over the 16 cn-lanes (same lg = same row)
#pragma unroll
      for (int m = 8; m >= 1; m >>= 1) {
        apv = fmaxf(apv, __shfl_xor(apv, m, 64));
        anv = fminf(anv, __shfl_xor(anv, m, 64));
      }
      if (cn == 0) {
        int R = bi * 128 + rl;
        atomicMax(&ap[R], __float_as_uint(apv));
        atomicMin(&an[R], __float_as_uint(anv));
      }
    }
  }
  // col side: reduce over lg (xor 16,32) -> full 64 rows per column
#pragma unroll
  for (int ni = 0; ni < 4; ++ni) {
    float a = cap[ni], b = can[ni];
#pragma unroll
    for (int m = 16; m <= 32; m <<= 1) {
      a = fmaxf(a, __shfl_xor(a, m, 64));
      b = fminf(b, __shfl_xor(b, m, 64));
    }
    if (lg == 0) {
      int C = bj * 128 + wn * 64 + ni * 16 + cn;
      atomicMax(&ap[C], __float_as_uint(a));
      atomicMin(&an[C], __float_as_uint(b));
    }
  }
#undef LOAD_TILE
#undef STORE_TILE
}

// ---------------------------------------------------------------------------
// Kernel 3: loss = mean(relu(margin + dist_ap - dist_an))
// ---------------------------------------------------------------------------
__global__ __launch_bounds__(256) void finalize_kernel(
    const unsigned* __restrict__ ap, const unsigned* __restrict__ an,
    float* __restrict__ out)
{
  const int t = threadIdx.x;
  float s = 0.f;
  for (int i = t; i < N_ROWS; i += 256) {
    float a = __uint_as_float(ap[i]);
    float b = __uint_as_float(an[i]);
    s += fmaxf(MARGIN + a - b, 0.0f);
  }
#pragma unroll
  for (int m = 32; m >= 1; m >>= 1) s += __shfl_down(s, m, 64);
  __shared__ float wsum[4];
  const int lane = t & 63, w = t >> 6;
  if (lane == 0) wsum[w] = s;
  __syncthreads();
  if (t == 0) out[0] = (wsum[0] + wsum[1] + wsum[2] + wsum[3]) * (1.0f / N_ROWS);
}

extern "C" void kernel_launch(void* const* d_in, const int* in_sizes, int n_in,
                              void* d_out, int out_size, void* d_ws, size_t ws_size,
                              hipStream_t stream) {
  const float* X = (const float*)d_in[0];
  const int* lab = (const int*)d_in[1];
  float* out = (float*)d_out;

  char* ws = (char*)d_ws;
  unsigned short* Xbf = (unsigned short*)ws;                          // 16 MB
  float* sq  = (float*)(ws + (size_t)N_ROWS * N_DIM * 2);             // 16 KB
  unsigned* ap = (unsigned*)((char*)sq + N_ROWS * sizeof(float));     // 16 KB
  unsigned* an = (unsigned*)((char*)ap + N_ROWS * sizeof(unsigned));  // 16 KB

  prep_kernel<<<N_ROWS / 4, 256, 0, stream>>>(X, Xbf, sq, ap, an);
  dist_kernel<<<NTILE * (NTILE + 1) / 2, 256, 0, stream>>>(Xbf, sq, lab, ap, an);
  finalize_kernel<<<1, 256, 0, stream>>>(ap, an, out);
}

// Round 5
// 149.416 us; speedup vs baseline: 1.5050x; 1.1669x over previous
//
#include <hip/hip_runtime.h>
#include <stdint.h>

#define N_ROWS 4096
#define N_DIM  2048
#define MARGIN 0.3f
#define NTILE  32            // 4096 / 128 tiles per side
#define NITER  (N_DIM / 64)  // 32 K-iterations of BK=64
#define FLTMAX 3.402823466e+38f

typedef __attribute__((ext_vector_type(8))) short short8;
typedef __attribute__((ext_vector_type(4))) float floatx4;

// Packed layout ("fragment order"): for row-group b (16 rows) and k-chunk c
// (32 k), a 1 KB block at shorts-offset (b*64+c)*512. Within the block,
// lane l's 16 B fragment at l*8 shorts = row b*16+(l&15), k c*32+(l>>4)*8..+8.
// This is byte-identical to the LDS slot layout R1-R4 verified (absmax 0.0).

__device__ inline unsigned short f2bf_rne(float f) {
  unsigned u = __float_as_uint(f);
  unsigned r = 0x7fffu + ((u >> 16) & 1u);
  return (unsigned short)((u + r) >> 16);
}
__device__ inline float bf2f(unsigned short h) {
  return __uint_as_float(((unsigned)h) << 16);
}

// ---------------------------------------------------------------------------
// Kernel 1: cast fp32 -> bf16 AND repack into fragment order; sq[i] from the
// ROUNDED values; init per-row reduction cells. One block per 16-row group.
// Thread map: r = t&15 (row), j = (t>>4)&3 (k-subchunk of 8), w = t>>6.
// Step s handles k-chunk c = w + 4*s. Writes are 1 KB contiguous per wave.
// ---------------------------------------------------------------------------
__global__ __launch_bounds__(256) void prep_kernel(
    const float* __restrict__ X, unsigned short* __restrict__ Xp,
    float* __restrict__ sq, unsigned* __restrict__ ap, unsigned* __restrict__ an)
{
  const int b = blockIdx.x;
  const int t = threadIdx.x;
  const int r = t & 15, j = (t >> 4) & 3, w = t >> 6;
  const float* Xg = X + ((size_t)b * 16 + r) * N_DIM + j * 8;
  unsigned short* Op = Xp + (size_t)b * 64 * 512 + (size_t)(j * 16 + r) * 8;
  float acc = 0.f;
#pragma unroll
  for (int s = 0; s < 16; ++s) {
    const int c = w + s * 4;
    float4 v0 = *(const float4*)(Xg + c * 32);
    float4 v1 = *(const float4*)(Xg + c * 32 + 4);
    short8 o;
    o[0] = (short)f2bf_rne(v0.x); o[1] = (short)f2bf_rne(v0.y);
    o[2] = (short)f2bf_rne(v0.z); o[3] = (short)f2bf_rne(v0.w);
    o[4] = (short)f2bf_rne(v1.x); o[5] = (short)f2bf_rne(v1.y);
    o[6] = (short)f2bf_rne(v1.z); o[7] = (short)f2bf_rne(v1.w);
#pragma unroll
    for (int e = 0; e < 8; ++e) {
      float f = bf2f((unsigned short)o[e]);
      acc = fmaf(f, f, acc);
    }
    *(short8*)(Op + (size_t)c * 512) = o;
  }
  // threads sharing a row are lanes {r, r+16, r+32, r+48} of each wave
  acc += __shfl_xor(acc, 16, 64);
  acc += __shfl_xor(acc, 32, 64);
  __shared__ float part[4][16];
  if ((t & 63) < 16) part[w][r] = acc;
  __syncthreads();
  if (t < 16) {
    float s4 = part[0][t] + part[1][t] + part[2][t] + part[3][t];
    sq[b * 16 + t] = s4;
    ap[b * 16 + t] = 0u;           // max identity (dist >= 0)
    an[b * 16 + t] = 0x7f7fffffu;  // FLT_MAX bits
  }
}

// ---------------------------------------------------------------------------
// Kernel 2: upper-triangle 128x128 tiles of G = X X^T. NO LDS tiles, NO
// barriers in the K-loop: every MFMA fragment is loaded straight from the
// packed global array as a fully-coalesced 1 KB global_load_dwordx4
// (lane l -> base + 16*l). Register ping-pong gives 1-iteration prefetch;
// MFMAs wait at vmcnt(16), never a full drain, and with no barriers the 8
// resident waves/CU drift freely to hide each other's latency.
// Each wave's 64x64 output feeds BOTH row-side and (symmetry) col-side
// hardest-pos/neg reductions.
// ---------------------------------------------------------------------------
__global__ __launch_bounds__(256, 2) void dist_kernel(
    const unsigned short* __restrict__ Xp, const float* __restrict__ sq,
    const int* __restrict__ lab, unsigned* __restrict__ ap, unsigned* __restrict__ an)
{
  __shared__ float sqi[128], sqj[128];
  __shared__ int labi[128], labj[128];

  // decode linear block id -> (bi, bj) with bi <= bj
  int p = blockIdx.x;
  int bi = 0;
  while (p >= NTILE - bi) { p -= NTILE - bi; ++bi; }
  const int bj = bi + p;

  const int t = threadIdx.x;
  const int lane = t & 63, w = t >> 6;     // 4 waves
  const int wm = w >> 1, wn = w & 1;       // 2x2 wave grid, 64x64 per wave

  if (t < 128) { int rr = bi * 128 + t; sqi[t] = sq[rr]; labi[t] = lab[rr]; }
  else         { int cc = bj * 128 + (t - 128); sqj[t - 128] = sq[cc]; labj[t - 128] = lab[cc]; }
  __syncthreads();   // once; K-loop below is barrier-free

  // fragment base offsets (in shorts); per (it,kh) add it*1024 + kh*512
  unsigned aoff[4], boff[4];
#pragma unroll
  for (int mi = 0; mi < 4; ++mi)
    aoff[mi] = (unsigned)(bi * 8 + wm * 4 + mi) * 64 * 512 + lane * 8;
#pragma unroll
  for (int ni = 0; ni < 4; ++ni)
    boff[ni] = (unsigned)(bj * 8 + wn * 4 + ni) * 64 * 512 + lane * 8;

  short8 fa[2][4][2], fb[2][4][2];   // [buf][frag][kh]

#define LOADF(BUF, IT)                                                        \
  do {                                                                        \
    _Pragma("unroll")                                                         \
    for (int mi = 0; mi < 4; ++mi) {                                          \
      _Pragma("unroll")                                                       \
      for (int kh = 0; kh < 2; ++kh)                                          \
        fa[BUF][mi][kh] = *(const short8*)(Xp + aoff[mi] + (IT) * 1024 + kh * 512); \
    }                                                                         \
    _Pragma("unroll")                                                         \
    for (int ni = 0; ni < 4; ++ni) {                                          \
      _Pragma("unroll")                                                       \
      for (int kh = 0; kh < 2; ++kh)                                          \
        fb[BUF][ni][kh] = *(const short8*)(Xp + boff[ni] + (IT) * 1024 + kh * 512); \
    }                                                                         \
  } while (0)

  LOADF(0, 0);

  floatx4 acc[4][4] = {};

#pragma unroll 2
  for (int it = 0; it < NITER; ++it) {
    const int cb = it & 1;
    if (it + 1 < NITER) LOADF(cb ^ 1, it + 1);   // prefetch; overlaps MFMAs below
#pragma unroll
    for (int kh = 0; kh < 2; ++kh)
#pragma unroll
      for (int mi = 0; mi < 4; ++mi)
#pragma unroll
        for (int ni = 0; ni < 4; ++ni)
          acc[mi][ni] = __builtin_amdgcn_mfma_f32_16x16x32_bf16(
              fa[cb][mi][kh], fb[cb][ni][kh], acc[mi][ni], 0, 0, 0);
  }
#undef LOADF

  // Epilogue. C/D layout (m89): col = lane&15, row = (lane>>4)*4 + reg.
  const int cn = lane & 15, lg = lane >> 4;
  float sqc[4]; int labc[4];
#pragma unroll
  for (int ni = 0; ni < 4; ++ni) {
    int c = wn * 64 + ni * 16 + cn;
    sqc[ni] = sqj[c]; labc[ni] = labj[c];
  }
  float cap[4] = {0.f, 0.f, 0.f, 0.f};
  float can[4] = {FLTMAX, FLTMAX, FLTMAX, FLTMAX};
#pragma unroll
  for (int mi = 0; mi < 4; ++mi) {
#pragma unroll
    for (int r = 0; r < 4; ++r) {
      const int rl = wm * 64 + mi * 16 + lg * 4 + r;   // row within 128-tile
      const float si = sqi[rl];
      const int li = labi[rl];
      float apv = 0.0f;
      float anv = FLTMAX;
#pragma unroll
      for (int ni = 0; ni < 4; ++ni) {
        float g = acc[mi][ni][r];
        float d2 = fmaf(-2.0f, g, si + sqc[ni]);
        d2 = fmaxf(d2, 1e-12f);
        float d = __builtin_amdgcn_sqrtf(d2);
        const bool same = (li == labc[ni]);
        const float dp = same ? d : 0.0f;
        const float dn = same ? FLTMAX : d;
        apv = fmaxf(apv, dp);
        anv = fminf(anv, dn);
        cap[ni] = fmaxf(cap[ni], dp);   // col-side (symmetric) partials
        can[ni] = fminf(can[ni], dn);
      }
      // row side: reduce over the 16 cn-lanes (same lg = same row)
#pragma unroll
      for (int m = 8; m >= 1; m >>= 1) {
        apv = fmaxf(apv, __shfl_xor(apv, m, 64));
        anv = fminf(anv, __shfl_xor(anv, m, 64));
      }
      if (cn == 0) {
        int R = bi * 128 + rl;
        atomicMax(&ap[R], __float_as_uint(apv));
        atomicMin(&an[R], __float_as_uint(anv));
      }
    }
  }
  // col side: reduce over lg (xor 16,32) -> full 64 rows per column
#pragma unroll
  for (int ni = 0; ni < 4; ++ni) {
    float a = cap[ni], b = can[ni];
#pragma unroll
    for (int m = 16; m <= 32; m <<= 1) {
      a = fmaxf(a, __shfl_xor(a, m, 64));
      b = fminf(b, __shfl_xor(b, m, 64));
    }
    if (lg == 0) {
      int C = bj * 128 + wn * 64 + ni * 16 + cn;
      atomicMax(&ap[C], __float_as_uint(a));
      atomicMin(&an[C], __float_as_uint(b));
    }
  }
}

// ---------------------------------------------------------------------------
// Kernel 3: loss = mean(relu(margin + dist_ap - dist_an))
// ---------------------------------------------------------------------------
__global__ __launch_bounds__(256) void finalize_kernel(
    const unsigned* __restrict__ ap, const unsigned* __restrict__ an,
    float* __restrict__ out)
{
  const int t = threadIdx.x;
  float s = 0.f;
  for (int i = t; i < N_ROWS; i += 256) {
    float a = __uint_as_float(ap[i]);
    float b = __uint_as_float(an[i]);
    s += fmaxf(MARGIN + a - b, 0.0f);
  }
#pragma unroll
  for (int m = 32; m >= 1; m >>= 1) s += __shfl_down(s, m, 64);
  __shared__ float wsum[4];
  const int lane = t & 63, w = t >> 6;
  if (lane == 0) wsum[w] = s;
  __syncthreads();
  if (t == 0) out[0] = (wsum[0] + wsum[1] + wsum[2] + wsum[3]) * (1.0f / N_ROWS);
}

extern "C" void kernel_launch(void* const* d_in, const int* in_sizes, int n_in,
                              void* d_out, int out_size, void* d_ws, size_t ws_size,
                              hipStream_t stream) {
  const float* X = (const float*)d_in[0];
  const int* lab = (const int*)d_in[1];
  float* out = (float*)d_out;

  char* ws = (char*)d_ws;
  unsigned short* Xp = (unsigned short*)ws;                           // 16 MB packed
  float* sq  = (float*)(ws + (size_t)N_ROWS * N_DIM * 2);             // 16 KB
  unsigned* ap = (unsigned*)((char*)sq + N_ROWS * sizeof(float));     // 16 KB
  unsigned* an = (unsigned*)((char*)ap + N_ROWS * sizeof(unsigned));  // 16 KB

  prep_kernel<<<N_ROWS / 16, 256, 0, stream>>>(X, Xp, sq, ap, an);
  dist_kernel<<<NTILE * (NTILE + 1) / 2, 256, 0, stream>>>(Xp, sq, lab, ap, an);
  finalize_kernel<<<1, 256, 0, stream>>>(ap, an, out);
}